// Round 8
// baseline (632.468 us; speedup 1.0000x reference)
//
#include <hip/hip_runtime.h>
#include <stdint.h>

#define EMB 128
#define PCAP 12288          // pairs stride per bucket (real edges; avg <=7700)
#define SCAP 13312          // stage capacity (padded edges per bucket)
#define TSHIFT 15           // src-tile = 32768 rows (<=4MB bf16 half-rows)

static constexpr int N_USER = 200000, N_VIDEO = 100000, N_PUB = 20000, N_TAG = 5000;
static constexpr int ROW_U = 0, ROW_V = 200000, ROW_P = 300000, ROW_T = 320000;
static constexpr int ROWS = 325000;           // + 1 extra zero row at index ROWS
static constexpr int TOTAL_E = 7000000;
static constexpr int TOTAL_GROUPS = 650000;
static constexpr int TILE = 8192;
static constexpr int SORT_MAX = TOTAL_E + 7 * TOTAL_GROUPS;

using f32x4 = __attribute__((ext_vector_type(4))) float;
using u32x4 = __attribute__((ext_vector_type(4))) unsigned int;
using u32x2 = __attribute__((ext_vector_type(2))) unsigned int;
using i32x4 = __attribute__((ext_vector_type(4))) int;

// ---------- bf16 helpers ----------
__device__ inline unsigned bf16_rne(float f) {
  unsigned u = __float_as_uint(f);
  return (u + 0x7fffu + ((u >> 16) & 1u)) >> 16;
}
__device__ inline unsigned pack_bf16x2(float lo, float hi) {
  return bf16_rne(lo) | (bf16_rne(hi) << 16);
}

// ---------- fp8 e4m3fn helpers ----------
__device__ inline unsigned fp8enc(float f) {
  unsigned b = __float_as_uint(f);
  unsigned s = (b >> 24) & 0x80u;
  unsigned ae = b & 0x7FFFFFFFu;
  unsigned r = ae + 0x7FFFFu + ((ae >> 20) & 1u);   // RNE at bit 20
  unsigned e = r >> 23;
  if (e < 121u) {                                   // |v| < 2^-6 -> fp8 subnormal
    float av = __uint_as_float(ae);
    unsigned m = (unsigned)__builtin_rintf(av * 512.0f);
    return s | m;
  }
  return s | ((e - 120u) << 3) | ((r >> 20) & 7u);
}
#if __has_builtin(__builtin_amdgcn_cvt_f32_fp8)
#define DEC4(w, x0, x1, x2, x3) \
  x0 += __builtin_amdgcn_cvt_f32_fp8((int)(w), 0); \
  x1 += __builtin_amdgcn_cvt_f32_fp8((int)(w), 1); \
  x2 += __builtin_amdgcn_cvt_f32_fp8((int)(w), 2); \
  x3 += __builtin_amdgcn_cvt_f32_fp8((int)(w), 3);
#else
__device__ inline float fp8dec(unsigned b) {
  unsigned s = (b & 0x80u) << 24;
  unsigned e = (b >> 3) & 0xFu;
  unsigned m = b & 7u;
  if (e == 0) { float f = (float)m * 0.001953125f; return s ? -f : f; }
  return __uint_as_float(s | ((e + 120u) << 23) | (m << 20));
}
#define DEC4(w, x0, x1, x2, x3) \
  x0 += fp8dec((w) & 0xffu); x1 += fp8dec(((w) >> 8) & 0xffu); \
  x2 += fp8dec(((w) >> 16) & 0xffu); x3 += fp8dec(((w) >> 24) & 0xffu);
#endif

// ---------- descriptors ----------
struct SortDesc {
  int tcum[9];
  int bcum[9];
  int gcum[8];
  int E[8];
  int n_dst[8];
  int wshift[8];
  int ntile[8];           // ceil(n_src / 2^TSHIFT)
  int zrow[8];            // ROWS - src_base[r]: local sentinel -> global zero row
  const int* esrc[8];
  const int* edst[8];
};

struct AggrDesc {
  int cum[9];
  int src_base[8];
  int src_col[8];
  int dst_base[8];
  int dst_col[8];
  const float* demb[8];
};

// ---------- pass 1: bin edges into dst-range buckets ----------
__global__ __launch_bounds__(256) void part_kernel(SortDesc d, unsigned* __restrict__ pairs,
                                                   int* __restrict__ cursors) {
  __shared__ int cnt[256];
  __shared__ int lcur[256];
  int blk = blockIdx.x;
  int r = 0;
#pragma unroll
  for (int k = 1; k < 8; ++k) if (blk >= d.tcum[k]) r = k;
  int base = (blk - d.tcum[r]) * TILE;
  int n = min(TILE, d.E[r] - base);
  const int* __restrict__ esrc = d.esrc[r];
  const int* __restrict__ edst = d.edst[r];
  int tid = threadIdx.x;
  int B = d.bcum[r + 1] - d.bcum[r];
  int sh = d.wshift[r];
  int msk = (1 << sh) - 1;
  int bb = d.bcum[r];
  if (tid < B) cnt[tid] = 0;
  __syncthreads();
  for (int i = tid; i < n; i += 256)
    atomicAdd(&cnt[edst[base + i] >> sh], 1);
  __syncthreads();
  if (tid < B) {
    int c = cnt[tid];
    lcur[tid] = c ? atomicAdd(&cursors[bb + tid], c) : 0;
  }
  __syncthreads();
  for (int i = tid; i < n; i += 256) {
    int dv = edst[base + i];
    int sv = esrc[base + i];
    int b = dv >> sh;
    int pos = atomicAdd(&lcur[b], 1);
    if (pos < PCAP)
      pairs[(size_t)(bb + b) * PCAP + pos] = ((unsigned)(dv & msk) << 18) | (unsigned)sv;
  }
}

// ---------- pass 2: per-bucket counting sort keyed (dst_local, src_tile) ----------
// Within each dst's list, edges are ordered by 32K-row src tiles (L2 locality);
// lists padded to multiple of 4 with the zero-row sentinel.
__global__ __launch_bounds__(256) void build_kernel(SortDesc d, const unsigned* __restrict__ pairs,
                                                    const int* __restrict__ cursors,
                                                    int* __restrict__ gcounter,
                                                    int* __restrict__ sorted,
                                                    int* __restrict__ Beg, int* __restrict__ Deg) {
  __shared__ int bins[4096];    // (dst_local * T + tile) counts -> cursors
  __shared__ int stage[SCAP];
  __shared__ int wsums[4];
  __shared__ int sh_gbase, sh_tot;
  int bucket = blockIdx.x;
  int r = 0;
#pragma unroll
  for (int k = 1; k < 8; ++k) if (bucket >= d.bcum[k]) r = k;
  int bl = bucket - d.bcum[r];
  int sh = d.wshift[r];
  int T = d.ntile[r];
  int first = bl << sh;
  int W = 1 << sh;
  int Wa = min(W, d.n_dst[r] - first);
  int zr = d.zrow[r];
  int tid = threadIdx.x;
  int n_b = min(cursors[bucket], PCAP);
  const unsigned* __restrict__ bp = pairs + (size_t)bucket * PCAP;

  int NB = W * T;               // total bins (<= 4096)
  for (int i = tid; i < NB; i += 256) bins[i] = 0;
  __syncthreads();
  for (int i = tid; i < n_b; i += 256) {
    unsigned pr = bp[i];
    atomicAdd(&bins[(int)(pr >> 18) * T + (int)((pr & 0x3FFFFu) >> TSHIFT)], 1);
  }
  __syncthreads();

  // per-dst counts (4 dsts per thread), pad to multiple of 4
  int t4 = tid * 4;
  int c[4], p[4];
  int s = 0;
#pragma unroll
  for (int jj = 0; jj < 4; ++jj) {
    int cj = 0;
    if (t4 + jj < W)
      for (int t = 0; t < T; ++t) cj += bins[(t4 + jj) * T + t];
    c[jj] = cj;
    p[jj] = (cj + 3) & ~3;
    s += p[jj];
  }
  int lane = tid & 63, wv = tid >> 6;
  int v = s;
#pragma unroll
  for (int dd = 1; dd < 64; dd <<= 1) {
    int t = __shfl_up(v, dd);
    if (lane >= dd) v += t;
  }
  if (lane == 63) wsums[wv] = v;
  __syncthreads();
  if (tid == 0) {
    int run = 0;
#pragma unroll
    for (int k = 0; k < 4; ++k) { int t = wsums[k]; wsums[k] = run; run += t; }
  }
  __syncthreads();
  int ex = wsums[wv] + (v - s);
  if (tid == 255) {
    int tot = ex + s;
    sh_gbase = atomicAdd(gcounter, tot);
    sh_tot = min(tot, SCAP);
  }
  __syncthreads();
  int gbase = sh_gbase;

  // per-dst padded base; convert bins to within-bucket cursors; write Beg/Deg
  int o[4];
  {
    int run = ex;
#pragma unroll
    for (int jj = 0; jj < 4; ++jj) { o[jj] = run; run += p[jj]; }
  }
#pragma unroll
  for (int jj = 0; jj < 4; ++jj) {
    int j = t4 + jj;
    if (j < W) {
      int run = o[jj];
      for (int t = 0; t < T; ++t) {
        int tmp = bins[j * T + t];
        bins[j * T + t] = run;
        run += tmp;
      }
      if (j < Wa) {
        Beg[d.gcum[r] + first + j] = gbase + o[jj];
        Deg[d.gcum[r] + first + j] = c[jj];
      }
    }
  }
  __syncthreads();

  // counting-sort scatter (tile-ordered within each dst)
  for (int i = tid; i < n_b; i += 256) {
    unsigned pr = bp[i];
    int sv = (int)(pr & 0x3FFFFu);
    int pos = atomicAdd(&bins[(int)(pr >> 18) * T + (sv >> TSHIFT)], 1);
    if (pos < SCAP) stage[pos] = sv;
  }
  __syncthreads();
  // pad fill [o+c, o+p) with sentinel
#pragma unroll
  for (int jj = 0; jj < 4; ++jj) {
    int end_ = min(o[jj] + p[jj], SCAP);
    for (int k = o[jj] + c[jj]; k < end_; ++k) stage[k] = zr;
  }
  __syncthreads();

  int tot = sh_tot;
  for (int i = tid; i < tot; i += 256)
    sorted[gbase + i] = stage[i];
}

// ---------- f32 inputs -> bf16 feature buffer + zero rows ----------
__global__ void convert_kernel(const float* __restrict__ u, const float* __restrict__ v,
                               const float* __restrict__ p, const float* __restrict__ t,
                               uint16_t* __restrict__ featA, uint16_t* __restrict__ featB,
                               unsigned char* __restrict__ f1f8) {
  int idx = blockIdx.x * blockDim.x + threadIdx.x;
  const int total8 = (ROWS + 1) * EMB / 8;
  if (idx >= total8) return;
  int flat = idx * 8;
  int row = flat >> 7;
  if (row == ROWS) {
    uint4 z = {0u, 0u, 0u, 0u};
    *(uint4*)(featA + flat) = z;
    *(uint4*)(featB + flat) = z;
    if (f1f8) { uint2 z2 = {0u, 0u}; *(uint2*)(f1f8 + flat) = z2; }
    return;
  }
  int col = flat & 127;
  const float* s;
  if (row < ROW_V)      s = u + (size_t)row * EMB + col;
  else if (row < ROW_P) s = v + (size_t)(row - ROW_V) * EMB + col;
  else if (row < ROW_T) s = p + (size_t)(row - ROW_P) * EMB + col;
  else                  s = t + (size_t)(row - ROW_T) * EMB + col;
  float4 f0 = *(const float4*)s;
  float4 f1 = *((const float4*)s + 1);
  uint4 o;
  o.x = pack_bf16x2(f0.x, f0.y);
  o.y = pack_bf16x2(f0.z, f0.w);
  o.z = pack_bf16x2(f1.x, f1.y);
  o.w = pack_bf16x2(f1.z, f1.w);
  *(uint4*)(featA + flat) = o;
}

// ---------- hot kernel ----------
// M=0: gather bf16 -> write bf16                  (layer0, no-fp8 fallback)
// M=4: gather bf16 -> write bf16 + fp8 dual       (layer0, fp8 path)
// M=3: gather bf16 -> write fp8                   (layer1 fallback)
// M=1: gather fp8  -> write fp8                   (layer1 fp8 path)
// M=2: gather fp8  -> epilogue out = emb + 1/2 f1 + 1/3 f2 + 1/4 f3
#define ACC(q) \
  a0 += __uint_as_float((q).x << 16); a1 += __uint_as_float((q).x & 0xffff0000u); \
  a2 += __uint_as_float((q).y << 16); a3 += __uint_as_float((q).y & 0xffff0000u); \
  a4 += __uint_as_float((q).z << 16); a5 += __uint_as_float((q).z & 0xffff0000u); \
  a6 += __uint_as_float((q).w << 16); a7 += __uint_as_float((q).w & 0xffff0000u);

#define ACC8(qq) \
  DEC4((qq).x, a0, a1, a2, a3); DEC4((qq).y, a4, a5, a6, a7);

template<int M>
__global__ __launch_bounds__(256) void aggr_kernel(AggrDesc d,
    const uint16_t* __restrict__ gsrc_bf, const unsigned char* __restrict__ gsrc_f8,
    uint16_t* __restrict__ dst_bf, unsigned char* __restrict__ dst_f8,
    const uint16_t* __restrict__ f1_bf, const uint16_t* __restrict__ demb_bf,
    float* __restrict__ out,
    const int* __restrict__ sorted, const int* __restrict__ Beg,
    const int* __restrict__ Deg) {
  if ((M == 1 || M == 3) && blockIdx.x == 0 && threadIdx.x < 16) {
    uint2 z = {0u, 0u};
    *(uint2*)(dst_f8 + (size_t)ROWS * EMB + threadIdx.x * 8) = z;
  }
  int g = blockIdx.x * 32 + (threadIdx.x >> 3);
  if (g >= TOTAL_GROUPS) return;
  int lane = threadIdx.x & 7;
  int r = 0;
#pragma unroll
  for (int k = 1; k < 8; ++k) if (g >= d.cum[k]) r = k;
  int n = g - d.cum[r];
  int beg = Beg[g], dg = Deg[g];
  float recip = 1.0f / (float)(dg > 0 ? dg : 1);
  constexpr bool GB = (M == 0 || M == 3 || M == 4);   // gather bf16?
  const uint16_t* __restrict__ sb16 =
      GB ? gsrc_bf + (size_t)d.src_base[r] * EMB + d.src_col[r] + lane * 8 : nullptr;
  const unsigned char* __restrict__ sb8 =
      !GB ? gsrc_f8 + (size_t)d.src_base[r] * EMB + d.src_col[r] + lane * 8 : nullptr;
  float a0 = 0.f, a1 = 0.f, a2 = 0.f, a3 = 0.f, a4 = 0.f, a5 = 0.f, a6 = 0.f, a7 = 0.f;
  int P = (dg + 3) & ~3;        // padded length (multiple of 4)
  int n8 = P >> 3;              // full 8-chunks
  int has4 = P & 4;
  const int* ep = sorted + beg; // 16B-aligned
  i32x4 iA0 = {0,0,0,0}, iA1 = {0,0,0,0};
  if (n8 > 0) {
    iA0 = __builtin_nontemporal_load((const i32x4*)ep);
    iA1 = __builtin_nontemporal_load((const i32x4*)ep + 1);
  }
  for (int cch = 0; cch < n8; ++cch) {
    i32x4 iB0 = {0,0,0,0}, iB1 = {0,0,0,0};
    if (cch + 1 < n8) {
      iB0 = __builtin_nontemporal_load((const i32x4*)(ep + 8));
      iB1 = __builtin_nontemporal_load((const i32x4*)(ep + 8) + 1);
    }
    if (GB) {
      uint4 q0 = *(const uint4*)(sb16 + (size_t)iA0[0] * EMB);
      uint4 q1 = *(const uint4*)(sb16 + (size_t)iA0[1] * EMB);
      uint4 q2 = *(const uint4*)(sb16 + (size_t)iA0[2] * EMB);
      uint4 q3 = *(const uint4*)(sb16 + (size_t)iA0[3] * EMB);
      uint4 q4 = *(const uint4*)(sb16 + (size_t)iA1[0] * EMB);
      uint4 q5 = *(const uint4*)(sb16 + (size_t)iA1[1] * EMB);
      uint4 q6 = *(const uint4*)(sb16 + (size_t)iA1[2] * EMB);
      uint4 q7 = *(const uint4*)(sb16 + (size_t)iA1[3] * EMB);
      __builtin_amdgcn_sched_barrier(0);
      ACC(q0); ACC(q1); ACC(q2); ACC(q3);
      ACC(q4); ACC(q5); ACC(q6); ACC(q7);
    } else {
      uint2 q0 = *(const uint2*)(sb8 + (size_t)iA0[0] * EMB);
      uint2 q1 = *(const uint2*)(sb8 + (size_t)iA0[1] * EMB);
      uint2 q2 = *(const uint2*)(sb8 + (size_t)iA0[2] * EMB);
      uint2 q3 = *(const uint2*)(sb8 + (size_t)iA0[3] * EMB);
      uint2 q4 = *(const uint2*)(sb8 + (size_t)iA1[0] * EMB);
      uint2 q5 = *(const uint2*)(sb8 + (size_t)iA1[1] * EMB);
      uint2 q6 = *(const uint2*)(sb8 + (size_t)iA1[2] * EMB);
      uint2 q7 = *(const uint2*)(sb8 + (size_t)iA1[3] * EMB);
      __builtin_amdgcn_sched_barrier(0);
      ACC8(q0); ACC8(q1); ACC8(q2); ACC8(q3);
      ACC8(q4); ACC8(q5); ACC8(q6); ACC8(q7);
    }
    iA0 = iB0; iA1 = iB1; ep += 8;
  }
  if (has4) {
    i32x4 i0 = __builtin_nontemporal_load((const i32x4*)ep);
    if (GB) {
      uint4 q0 = *(const uint4*)(sb16 + (size_t)i0[0] * EMB);
      uint4 q1 = *(const uint4*)(sb16 + (size_t)i0[1] * EMB);
      uint4 q2 = *(const uint4*)(sb16 + (size_t)i0[2] * EMB);
      uint4 q3 = *(const uint4*)(sb16 + (size_t)i0[3] * EMB);
      __builtin_amdgcn_sched_barrier(0);
      ACC(q0); ACC(q1); ACC(q2); ACC(q3);
    } else {
      uint2 q0 = *(const uint2*)(sb8 + (size_t)i0[0] * EMB);
      uint2 q1 = *(const uint2*)(sb8 + (size_t)i0[1] * EMB);
      uint2 q2 = *(const uint2*)(sb8 + (size_t)i0[2] * EMB);
      uint2 q3 = *(const uint2*)(sb8 + (size_t)i0[3] * EMB);
      __builtin_amdgcn_sched_barrier(0);
      ACC8(q0); ACC8(q1); ACC8(q2); ACC8(q3);
    }
  }
  a0 *= recip; a1 *= recip; a2 *= recip; a3 *= recip;
  a4 *= recip; a5 *= recip; a6 *= recip; a7 *= recip;

  int col = d.dst_col[r] + lane * 8;
  size_t dpos = (size_t)(d.dst_base[r] + n) * EMB + col;

  if (M == 0 || M == 4) {
    u32x4 ov;
    ov.x = pack_bf16x2(a0, a1);
    ov.y = pack_bf16x2(a2, a3);
    ov.z = pack_bf16x2(a4, a5);
    ov.w = pack_bf16x2(a6, a7);
    __builtin_nontemporal_store(ov, (u32x4*)(dst_bf + dpos));
    if (M == 4) {
      u32x2 o8;
      o8.x = fp8enc(a0) | (fp8enc(a1) << 8) | (fp8enc(a2) << 16) | (fp8enc(a3) << 24);
      o8.y = fp8enc(a4) | (fp8enc(a5) << 8) | (fp8enc(a6) << 16) | (fp8enc(a7) << 24);
      __builtin_nontemporal_store(o8, (u32x2*)(dst_f8 + dpos));
    }
    return;
  }
  if (M == 1 || M == 3) {
    u32x2 ov;
    ov.x = fp8enc(a0) | (fp8enc(a1) << 8) | (fp8enc(a2) << 16) | (fp8enc(a3) << 24);
    ov.y = fp8enc(a4) | (fp8enc(a5) << 8) | (fp8enc(a6) << 16) | (fp8enc(a7) << 24);
    __builtin_nontemporal_store(ov, (u32x2*)(dst_f8 + dpos));
    return;
  }

  // M == 2: final epilogue
  u32x4 q1 = __builtin_nontemporal_load((const u32x4*)(f1_bf + dpos));   // f1 bf16
  u32x2 qf = __builtin_nontemporal_load((const u32x2*)(gsrc_f8 + dpos)); // f2 fp8
  float g0 = 0.f, g1 = 0.f, g2 = 0.f, g3 = 0.f, g4 = 0.f, g5 = 0.f, g6 = 0.f, g7 = 0.f;
  DEC4(qf.x, g0, g1, g2, g3);
  DEC4(qf.y, g4, g5, g6, g7);
  f32x4 v0, v1;
  if (demb_bf) {          // bf16 input copy (tier 3): 83MB instead of 166MB
    u32x4 qe = __builtin_nontemporal_load((const u32x4*)(demb_bf + dpos));
    v0.x = __uint_as_float(qe.x << 16); v0.y = __uint_as_float(qe.x & 0xffff0000u);
    v0.z = __uint_as_float(qe.y << 16); v0.w = __uint_as_float(qe.y & 0xffff0000u);
    v1.x = __uint_as_float(qe.z << 16); v1.y = __uint_as_float(qe.z & 0xffff0000u);
    v1.z = __uint_as_float(qe.w << 16); v1.w = __uint_as_float(qe.w & 0xffff0000u);
  } else {
    const f32x4* de = (const f32x4*)(d.demb[r] + (size_t)n * EMB + col);
    v0 = __builtin_nontemporal_load(de);
    v1 = __builtin_nontemporal_load(de + 1);
  }
  const float w1 = 0.5f, w2 = 1.0f / 3.0f, w3 = 0.25f;
  v0.x += w1 * __uint_as_float(q1.x << 16)         + w2 * g0 + w3 * a0;
  v0.y += w1 * __uint_as_float(q1.x & 0xffff0000u) + w2 * g1 + w3 * a1;
  v0.z += w1 * __uint_as_float(q1.y << 16)         + w2 * g2 + w3 * a2;
  v0.w += w1 * __uint_as_float(q1.y & 0xffff0000u) + w2 * g3 + w3 * a3;
  v1.x += w1 * __uint_as_float(q1.z << 16)         + w2 * g4 + w3 * a4;
  v1.y += w1 * __uint_as_float(q1.z & 0xffff0000u) + w2 * g5 + w3 * a5;
  v1.z += w1 * __uint_as_float(q1.w << 16)         + w2 * g6 + w3 * a6;
  v1.w += w1 * __uint_as_float(q1.w & 0xffff0000u) + w2 * g7 + w3 * a7;
  __builtin_nontemporal_store(v0, (f32x4*)(out + dpos));
  __builtin_nontemporal_store(v1, (f32x4*)(out + dpos) + 1);
}

// ---------- host ----------
extern "C" void kernel_launch(void* const* d_in, const int* in_sizes, int n_in,
                              void* d_out, int out_size, void* d_ws, size_t ws_size,
                              hipStream_t stream) {
  const float* emb_u = (const float*)d_in[0];
  const float* emb_v = (const float*)d_in[1];
  const float* emb_p = (const float*)d_in[2];
  const float* emb_t = (const float*)d_in[3];

  struct RelInfo { int si, di, E, n_dst, src_base, src_col, dst_base, dst_col, wshift, n_src; };
  const RelInfo rels[8] = {
    {12, 13,  800000, N_TAG,   ROW_V, 64, ROW_T,  0,  5, N_VIDEO},  // vt
    {16, 17,  400000, N_TAG,   ROW_P, 64, ROW_T, 64,  5, N_PUB},    // pt
    { 8,  9,  800000, N_PUB,   ROW_U, 64, ROW_P,  0,  7, N_USER},   // up
    {18, 19,  400000, N_PUB,   ROW_T, 64, ROW_P, 64,  7, N_TAG},    // tp
    { 4,  5, 1500000, N_VIDEO, ROW_U,  0, ROW_V,  0,  9, N_USER},   // uv
    {14, 15,  800000, N_VIDEO, ROW_T,  0, ROW_V, 64,  9, N_TAG},    // tv
    { 6,  7, 1500000, N_USER,  ROW_V,  0, ROW_U,  0, 10, N_VIDEO},  // vu
    {10, 11,  800000, N_USER,  ROW_P,  0, ROW_U, 64, 10, N_PUB},    // pu
  };
  const float* dembs[8] = {emb_t, emb_t, emb_p, emb_p, emb_v, emb_v, emb_u, emb_u};

  char* ws = (char*)d_ws;
  size_t cursor = 0;
  auto take = [&](size_t bytes) -> char* {
    char* p = ws + cursor;
    cursor = (cursor + bytes + 255) & ~(size_t)255;
    return p;
  };
  uint16_t* featA = (uint16_t*)take((size_t)(ROWS + 1) * EMB * 2);
  uint16_t* featB = (uint16_t*)take((size_t)(ROWS + 1) * EMB * 2);
  int* sorted = (int*)take((size_t)SORT_MAX * 4);
  int* Beg    = (int*)take((size_t)TOTAL_GROUPS * 4);
  int* Deg    = (int*)take((size_t)TOTAL_GROUPS * 4);
  unsigned* pairs = (unsigned*)d_ws;   // alias over featA/featB (dead before convert)

  SortDesc sd;
  AggrDesc ad;
  int tacc = 0, bacc = 0, gacc = 0;
  for (int r = 0; r < 8; ++r) {
    int n_dst = rels[r].n_dst;
    sd.tcum[r] = tacc; tacc += (rels[r].E + TILE - 1) / TILE;
    sd.bcum[r] = bacc; bacc += (n_dst + (1 << rels[r].wshift) - 1) >> rels[r].wshift;
    sd.gcum[r] = gacc;
    sd.E[r] = rels[r].E;
    sd.n_dst[r] = n_dst;
    sd.wshift[r] = rels[r].wshift;
    sd.ntile[r] = (rels[r].n_src + (1 << TSHIFT) - 1) >> TSHIFT;
    sd.zrow[r] = ROWS - rels[r].src_base;
    sd.esrc[r] = (const int*)d_in[rels[r].si];
    sd.edst[r] = (const int*)d_in[rels[r].di];

    ad.cum[r] = gacc;
    ad.src_base[r] = rels[r].src_base;
    ad.src_col[r] = rels[r].src_col;
    ad.dst_base[r] = rels[r].dst_base;
    ad.dst_col[r] = rels[r].dst_col;
    ad.demb[r] = dembs[r];
    gacc += n_dst;
  }
  sd.tcum[8] = tacc;
  sd.bcum[8] = bacc;
  ad.cum[8] = gacc;    // 650000

  int* cursors  = (int*)take((size_t)bacc * 4 + 4);
  int* gcounter = cursors + bacc;

  // tier allocations (fp8 f1 buffer; standalone f2 buffer)
  const size_t f8bytes = (size_t)(ROWS + 1) * EMB;   // 41.6 MB
  size_t base_need = cursor;
  unsigned char* f1fp8 = nullptr;
  unsigned char* f2fp8 = (unsigned char*)featA;      // default: alias dead featA
  bool use_fp8_l1 = false;
  const uint16_t* demb_bf = nullptr;                 // tier 3: epilogue reads bf16 emb
  if (ws_size >= base_need + f8bytes + 256) {        // tier 2
    f1fp8 = (unsigned char*)take(f8bytes);
    use_fp8_l1 = true;
    if (ws_size >= cursor + f8bytes + 256) {         // tier 3: keep featA alive
      f2fp8 = (unsigned char*)take(f8bytes);
      demb_bf = featA;
    }
  }

  // ---- CSR build (tile-sorted, padded to multiples of 4 per dst)
  hipMemsetAsync(cursors, 0, (size_t)(bacc + 1) * 4, stream);
  part_kernel<<<tacc, 256, 0, stream>>>(sd, pairs, cursors);
  build_kernel<<<bacc, 256, 0, stream>>>(sd, pairs, cursors, gcounter, sorted, Beg, Deg);

  // ---- bf16 feature init (pairs region dead) + zero rows
  convert_kernel<<<((ROWS + 1) * EMB / 8 + 255) / 256, 256, 0, stream>>>(
      emb_u, emb_v, emb_p, emb_t, featA, featB, f1fp8);

  float* out = (float*)d_out;
  const int aggr_blocks = (TOTAL_GROUPS + 31) / 32;
  if (use_fp8_l1) {
    aggr_kernel<4><<<aggr_blocks, 256, 0, stream>>>(ad, featA, nullptr, featB, f1fp8,
                                                    nullptr, nullptr, nullptr, sorted, Beg, Deg);
    aggr_kernel<1><<<aggr_blocks, 256, 0, stream>>>(ad, nullptr, f1fp8, nullptr, f2fp8,
                                                    nullptr, nullptr, nullptr, sorted, Beg, Deg);
  } else {
    aggr_kernel<0><<<aggr_blocks, 256, 0, stream>>>(ad, featA, nullptr, featB, nullptr,
                                                    nullptr, nullptr, nullptr, sorted, Beg, Deg);
    aggr_kernel<3><<<aggr_blocks, 256, 0, stream>>>(ad, featB, nullptr, nullptr, f2fp8,
                                                    nullptr, nullptr, nullptr, sorted, Beg, Deg);
  }
  aggr_kernel<2><<<aggr_blocks, 256, 0, stream>>>(ad, nullptr, f2fp8, nullptr, nullptr,
                                                  featB, demb_bf, out, sorted, Beg, Deg);
}